// Round 6
// baseline (929.541 us; speedup 1.0000x reference)
//
#include <hip/hip_runtime.h>

typedef __bf16 bf16;
typedef __attribute__((ext_vector_type(8))) __bf16 bf16x8;
typedef __attribute__((ext_vector_type(4))) __bf16 bf16x4;
typedef __attribute__((ext_vector_type(4))) float f32x4;

#define MFMA16(A, Bf, Cf) __builtin_amdgcn_mfma_f32_16x16x32_bf16((A), (Bf), (Cf), 0, 0, 0)

namespace {
constexpr int kB = 2048;
constexpr float kScale = 0.17677669529663687f;  // 1/sqrt(32)
constexpr size_t kOut0 = (size_t)kB * 64 * 256;  // out floats; attn follows
// ws layout (bytes)
constexpr size_t kWqkvOff = 0;         // bf16 [768][256]
constexpr size_t kWprojOff = 393216;   // bf16 [256][256]
constexpr size_t kBiasOff = 524288;    // f32  [8][4][4][64][4]  (S D-frag layout)
}

// Stash plan (no extra workspace; output buffers used as scratch, fully
// overwritten by the end):
//  - qk stash: bf16 [64][512] (q cols 0..255 pre-scaled, k cols 256..511) at
//    attn_out + b*32768 floats. K2 consumes it into regs/LDS BEFORE writing
//    any attn (single barrier orders all stash reads before attn writes).
//  - v stash:  bf16 [64][256] at out + b*16384 floats, bytes [0,32K).
//  - O stash:  bf16 [64][256] same window, bytes [32K,64K). K3 reads it,
//    barriers, then overwrites the whole window with final out.
// Kernel boundaries (same stream) order K1 -> K2 -> K3.

// ---- prep: fp32->bf16 weights + bias permuted to S-fragment layout ----------
__global__ void prep_kernel(const float* __restrict__ qkv_w,
                            const float* __restrict__ proj_w,
                            const float* __restrict__ bias_table,
                            const int* __restrict__ rel_idx,
                            bf16* __restrict__ qkv_wb,
                            bf16* __restrict__ proj_wb,
                            float* __restrict__ biasf) {
  int t = blockIdx.x * 256 + threadIdx.x;
  if (t < 196608) {
    qkv_wb[t] = (bf16)qkv_w[t];
  } else if (t < 262144) {
    int u = t - 196608;
    proj_wb[u] = (bf16)proj_w[u];
  } else if (t < 294912) {
    int u = t - 262144;          // u = h*4096 + wave*1024 + ct*256 + lane*4 + r
    int h = u >> 12;
    int v = u & 4095;
    int wv = v >> 10;
    int ct = (v >> 8) & 3;
    int lane = (v >> 2) & 63;
    int r = v & 3;
    int row = wv * 16 + (lane >> 4) * 4 + r;
    int col = ct * 16 + (lane & 15);
    biasf[u] = bias_table[rel_idx[row * 64 + col] * 8 + h];
  }
}

// ---- K1: QKV GEMM. 1 window/block, 4 waves in a 2x2 grid:
// wave=(wr,wc): wr=wave>>1 owns rows [32wr,32wr+32) (2 row-tiles of A-frags),
// wc=wave&1 owns cols [384wc,384wc+384) (24 col-tiles). Full 64x768 coverage,
// weight loads shared across 2 row-tiles (2x dedup vs 4x duplication), no
// barriers around the MFMA loop.
__launch_bounds__(256, 3)
__global__ void qkv_kernel(const float* __restrict__ x,
                           const float* __restrict__ qkv_b,
                           const bf16* __restrict__ qkv_wb,
                           float* __restrict__ out,
                           float* __restrict__ attn_out) {
  __shared__ __align__(16) bf16 xb[64 * 264];
  const int t = threadIdx.x;
  const int wave = t >> 6;
  const int lane = t & 63;
  const int l16 = lane & 15;
  const int quad = lane >> 4;
  const int b = blockIdx.x;
  const int wr = wave >> 1;   // row half
  const int wc = wave & 1;    // col half
  const f32x4 fz = {0.f, 0.f, 0.f, 0.f};

  {
    const f32x4* xv = (const f32x4*)(x + (size_t)b * 16384);
#pragma unroll
    for (int i = 0; i < 16; ++i) {
      int g4 = i * 256 + t;
      f32x4 v = xv[g4];
      int row = g4 >> 6;
      int c4 = (g4 & 63) << 2;
      bf16x4 w;
      w.x = (bf16)v.x; w.y = (bf16)v.y; w.z = (bf16)v.z; w.w = (bf16)v.w;
      *(bf16x4*)&xb[row * 264 + c4] = w;
    }
  }
  __syncthreads();

  // A-frags for the wave's TWO row-tiles (rows 32wr + rt*16 + l16)
  bf16x8 afr[2][8];
#pragma unroll
  for (int rt = 0; rt < 2; ++rt)
#pragma unroll
    for (int kt = 0; kt < 8; ++kt)
      afr[rt][kt] =
          *(const bf16x8*)&xb[(wr * 32 + rt * 16 + l16) * 264 + kt * 32 + quad * 8];

  bf16* qkst = (bf16*)(attn_out + (size_t)b * 32768);  // [64][512]
  bf16* vst  = (bf16*)(out + (size_t)b * 16384);       // [64][256]

#pragma unroll 2
  for (int nt = 0; nt < 24; ++nt) {
    int col16 = wc * 384 + nt * 16;          // tile's base output col
    const bf16* wp = qkv_wb + (col16 + l16) * 256 + quad * 8;
    bf16x8 bfr[8];
#pragma unroll
    for (int kt = 0; kt < 8; ++kt) bfr[kt] = *(const bf16x8*)&wp[kt * 32];
    f32x4 a0 = fz, a1 = fz;
#pragma unroll
    for (int kt = 0; kt < 8; ++kt) {
      a0 = MFMA16(afr[0][kt], bfr[kt], a0);
      a1 = MFMA16(afr[1][kt], bfr[kt], a1);
    }
    int col = col16 + l16;
    float qb = qkv_b[col];
    float sc = (col16 < 256) ? kScale : 1.0f;  // uniform per 16-col tile
#pragma unroll
    for (int rt = 0; rt < 2; ++rt) {
      f32x4 a = rt ? a1 : a0;
#pragma unroll
      for (int r = 0; r < 4; ++r) {
        int row = wr * 32 + rt * 16 + quad * 4 + r;
        float val = (a[r] + qb) * sc;          // bias then scale (ref order)
        if (col16 < 512) qkst[row * 512 + col] = (bf16)val;
        else             vst[row * 256 + (col - 512)] = (bf16)val;
      }
    }
  }
}

// ---- K2: attention. q-frags in regs, k in LDS (read-only all heads),
// v double-buffered+transposed per head, one barrier per head.
__launch_bounds__(256, 3)
__global__ void attn2_kernel(const float* __restrict__ biasf,
                             float* __restrict__ out,
                             float* __restrict__ attn_out) {
  __shared__ __align__(16) bf16 kl[64 * 264];   // k, all heads (cols 0..255)
  __shared__ __align__(16) bf16 vT[2][32 * 72]; // per-head v^T [d_local][token]
  __shared__ __align__(16) bf16 Pb[64 * 72];    // wave-private P

  const int t = threadIdx.x;
  const int wave = t >> 6;
  const int lane = t & 63;
  const int l16 = lane & 15;
  const int quad = lane >> 4;
  const int b = blockIdx.x;
  const int mrow = wave * 16 + l16;
  const f32x4 fz = {0.f, 0.f, 0.f, 0.f};

  const bf16* qkst = (const bf16*)(attn_out + (size_t)b * 32768);
  const bf16* vst  = (const bf16*)(out + (size_t)b * 16384);
  bf16* ost = (bf16*)(out + (size_t)b * 16384) + 16384;  // O stash [64][256]

  // q A-fragments for all 8 heads -> 32 VGPRs
  bf16x8 qf[8];
#pragma unroll
  for (int h = 0; h < 8; ++h)
    qf[h] = *(const bf16x8*)&qkst[mrow * 512 + h * 32 + quad * 8];

  // k -> LDS [64][264] (stash cols 256..511)
  {
    int row = t >> 2, part = t & 3;
#pragma unroll
    for (int j = 0; j < 8; ++j) {
      bf16x8 v = *(const bf16x8*)&qkst[row * 512 + 256 + part * 64 + j * 8];
      *(bf16x8*)&kl[row * 264 + part * 64 + j * 8] = v;
    }
  }
  // v head 0 -> vT[0]
  {
    int tok = t >> 2, dp = t & 3;
    bf16x8 v = *(const bf16x8*)&vst[tok * 256 + dp * 8];
#pragma unroll
    for (int j = 0; j < 8; ++j) vT[0][(dp * 8 + j) * 72 + tok] = v[j];
  }
  __syncthreads();  // staging visible; all qkst reads drained (attn writes
                    // below may clobber the stash region safely)

#pragma unroll
  for (int h = 0; h < 8; ++h) {
    // prefetch next head's v (global -> regs; written to LDS after PV)
    int tok = t >> 2, dp = t & 3;
    bf16x8 vnext;
    if (h < 7) vnext = *(const bf16x8*)&vst[tok * 256 + (h + 1) * 32 + dp * 8];

    f32x4 bfrag[4];
    const f32x4* bp4 = (const f32x4*)(biasf + h * 4096 + wave * 1024);
#pragma unroll
    for (int ct = 0; ct < 4; ++ct) bfrag[ct] = bp4[ct * 64 + lane];

    // S = q_h k_h^T + bias (K=32 -> 1 MFMA per 16x16 tile)
    f32x4 s[4];
#pragma unroll
    for (int ct = 0; ct < 4; ++ct) {
      bf16x8 bS = *(const bf16x8*)&kl[(ct * 16 + l16) * 264 + h * 32 + quad * 8];
      s[ct] = MFMA16(qf[h], bS, bfrag[ct]);
    }

    // softmax over j
#pragma unroll
    for (int r = 0; r < 4; ++r) {
      float m = fmaxf(fmaxf(s[0][r], s[1][r]), fmaxf(s[2][r], s[3][r]));
#pragma unroll
      for (int off = 8; off; off >>= 1) m = fmaxf(m, __shfl_xor(m, off));
      float e0 = __expf(s[0][r] - m);
      float e1 = __expf(s[1][r] - m);
      float e2 = __expf(s[2][r] - m);
      float e3 = __expf(s[3][r] - m);
      float sum = (e0 + e1) + (e2 + e3);
#pragma unroll
      for (int off = 8; off; off >>= 1) sum += __shfl_xor(sum, off);
      float is = 1.0f / sum;
      s[0][r] = e0 * is; s[1][r] = e1 * is; s[2][r] = e2 * is; s[3][r] = e3 * is;
    }

    // attn (fp32 global) + P (bf16 LDS, wave-private)
    float* ao = attn_out + ((size_t)(b * 8 + h) << 12);
#pragma unroll
    for (int ct = 0; ct < 4; ++ct)
#pragma unroll
      for (int r = 0; r < 4; ++r) {
        int i = wave * 16 + quad * 4 + r;
        int j = ct * 16 + l16;
        float pv = s[ct][r];
        ao[i * 64 + j] = pv;
        Pb[i * 72 + j] = (bf16)pv;
      }

    // O_h = P @ V
    f32x4 o[2];
    o[0] = fz; o[1] = fz;
#pragma unroll
    for (int ks = 0; ks < 2; ++ks) {
      bf16x8 aP = *(const bf16x8*)&Pb[mrow * 72 + ks * 32 + quad * 8];
#pragma unroll
      for (int nt = 0; nt < 2; ++nt) {
        bf16x8 bV = *(const bf16x8*)&vT[h & 1][(nt * 16 + l16) * 72 + ks * 32 + quad * 8];
        o[nt] = MFMA16(aP, bV, o[nt]);
      }
    }

    // O -> out-region stash
#pragma unroll
    for (int nt = 0; nt < 2; ++nt)
#pragma unroll
      for (int r = 0; r < 4; ++r)
        ost[(wave * 16 + quad * 4 + r) * 256 + h * 32 + nt * 16 + l16] =
            (bf16)o[nt][r];

    // vT[(h+1)&1]: last read at PV(h-1) (before barrier h-1); write here;
    // next read at PV(h+1) (after barrier h). Single barrier per head.
    if (h < 7) {
#pragma unroll
      for (int j = 0; j < 8; ++j)
        vT[(h + 1) & 1][(dp * 8 + j) * 72 + tok] = vnext[j];
    }
    __syncthreads();
  }
}

// ---- K3: proj GEMM. 1 window/block; barrier between stash reads and the
// out stores that overwrite the stash (cross-wave clobber).
__launch_bounds__(256, 3)
__global__ void proj_kernel(const float* __restrict__ proj_b,
                            const bf16* __restrict__ proj_wb,
                            float* __restrict__ out) {
  const int t = threadIdx.x;
  const int wave = t >> 6;
  const int lane = t & 63;
  const int l16 = lane & 15;
  const int quad = lane >> 4;
  const int b = blockIdx.x;
  const int mrow = wave * 16 + l16;
  const f32x4 fz = {0.f, 0.f, 0.f, 0.f};

  const bf16* ost = (const bf16*)(out + (size_t)b * 16384) + 16384;
  bf16x8 oafr[8];
#pragma unroll
  for (int kt = 0; kt < 8; ++kt)
    oafr[kt] = *(const bf16x8*)&ost[mrow * 256 + kt * 32 + quad * 8];

  f32x4 acc[16];
#pragma unroll
  for (int i = 0; i < 16; ++i) acc[i] = fz;
#pragma unroll
  for (int nt = 0; nt < 16; ++nt) {
    const bf16* wp = proj_wb + (nt * 16 + l16) * 256 + quad * 8;
    bf16x8 bfr[8];
#pragma unroll
    for (int kt = 0; kt < 8; ++kt) bfr[kt] = *(const bf16x8*)&wp[kt * 32];
#pragma unroll
    for (int kt = 0; kt < 8; ++kt) acc[nt] = MFMA16(oafr[kt], bfr[kt], acc[nt]);
  }
  __syncthreads();  // all waves' stash reads complete before stores clobber

  float* op = out + (size_t)b * 16384;
#pragma unroll
  for (int nt = 0; nt < 16; ++nt) {
    float pb = proj_b[nt * 16 + l16];
#pragma unroll
    for (int r = 0; r < 4; ++r)
      op[(wave * 16 + quad * 4 + r) * 256 + nt * 16 + l16] = acc[nt][r] + pb;
  }
}

extern "C" void kernel_launch(void* const* d_in, const int* in_sizes, int n_in,
                              void* d_out, int out_size, void* d_ws, size_t ws_size,
                              hipStream_t stream) {
  const float* x          = (const float*)d_in[0];
  const float* qkv_w      = (const float*)d_in[1];
  const float* qkv_b      = (const float*)d_in[2];
  const float* proj_w     = (const float*)d_in[3];
  const float* proj_b     = (const float*)d_in[4];
  const float* bias_table = (const float*)d_in[5];
  const int*   rel_idx    = (const int*)d_in[6];

  bf16*  qkv_wb = (bf16*)((char*)d_ws + kWqkvOff);
  bf16*  proj_wb = (bf16*)((char*)d_ws + kWprojOff);
  float* biasf  = (float*)((char*)d_ws + kBiasOff);

  float* out      = (float*)d_out;
  float* attn_out = out + kOut0;

  prep_kernel<<<1152, 256, 0, stream>>>(qkv_w, proj_w, bias_table, rel_idx,
                                        qkv_wb, proj_wb, biasf);
  qkv_kernel<<<kB, 256, 0, stream>>>(x, qkv_b, qkv_wb, out, attn_out);
  attn2_kernel<<<kB, 256, 0, stream>>>(biasf, out, attn_out);
  proj_kernel<<<kB, 256, 0, stream>>>(proj_b, proj_wb, out);
}

// Round 7
// 871.909 us; speedup vs baseline: 1.0661x; 1.0661x over previous
//
#include <hip/hip_runtime.h>

typedef __bf16 bf16;
typedef __attribute__((ext_vector_type(8))) __bf16 bf16x8;
typedef __attribute__((ext_vector_type(4))) __bf16 bf16x4;
typedef __attribute__((ext_vector_type(4))) float f32x4;

#define MFMA16(A, Bf, Cf) __builtin_amdgcn_mfma_f32_16x16x32_bf16((A), (Bf), (Cf), 0, 0, 0)

namespace {
constexpr int kB = 2048;
constexpr float kScale = 0.17677669529663687f;  // 1/sqrt(32)
constexpr size_t kOut0 = (size_t)kB * 64 * 256;  // out floats; attn follows
// ws layout (bytes)
constexpr size_t kWqkvOff = 0;         // bf16 [768][256]
constexpr size_t kWprojOff = 393216;   // bf16 [256][256]
constexpr size_t kBiasOff = 524288;    // f32  [8][4][4][64][4]  (S D-frag layout)
}

// Stash plan (no extra workspace; output buffers used as scratch, fully
// overwritten by the end). Per-window attn region = 128 KB:
//   bytes [0,64K):   qk stash bf16 [64][512] (q cols 0..255 pre-scaled, k 256..511)
//   bytes [64K,96K): x_bf16 [64][256] (written by prep, read by K1 only)
// Per-window out region = 64 KB:
//   bytes [0,32K):   v stash bf16 [64][256]
//   bytes [32K,64K): O stash bf16 [64][256]
// Stream order: fill(harness) -> prep -> K1 (qkv GEMM) -> K2 (attn) -> K3 (proj).
// K1 writes only stash bytes [0,64K) of attn slots + v stash: disjoint from the
// xbf bytes [64K,96K) it reads -> no cross-block hazard. K2 consumes window b's
// stash before its own attn writes (barrier-proven); xbf is dead after K1.

// ---- prep: weights->bf16, bias permute, x->bf16 into per-window slots ------
__global__ void prep_kernel(const float* __restrict__ x,
                            const float* __restrict__ qkv_w,
                            const float* __restrict__ proj_w,
                            const float* __restrict__ bias_table,
                            const int* __restrict__ rel_idx,
                            bf16* __restrict__ qkv_wb,
                            bf16* __restrict__ proj_wb,
                            float* __restrict__ biasf,
                            float* __restrict__ attn_out) {
  int t = blockIdx.x * 256 + threadIdx.x;
  if (t < 196608) {
    qkv_wb[t] = (bf16)qkv_w[t];
  } else if (t < 262144) {
    int u = t - 196608;
    proj_wb[u] = (bf16)proj_w[u];
  } else if (t < 294912) {
    int u = t - 262144;          // u = h*4096 + wave*1024 + ct*256 + lane*4 + r
    int h = u >> 12;
    int v = u & 4095;
    int wv = v >> 10;
    int ct = (v >> 8) & 3;
    int lane = (v >> 2) & 63;
    int r = v & 3;
    int row = wv * 16 + (lane >> 4) * 4 + r;
    int col = ct * 16 + (lane & 15);
    biasf[u] = bias_table[rel_idx[row * 64 + col] * 8 + h];
  } else if (t < 294912 + 4194304) {
    // x -> bf16, 8 elems/thread, into window slot attn[win] bytes [64K,96K)
    int u = t - 294912;
    size_t e = (size_t)u * 8;
    int win = (int)(e >> 14);
    int rem = (int)(e & 16383);
    int lrow = rem >> 8;
    int col = rem & 255;
    const f32x4* xs = (const f32x4*)(x + e);
    f32x4 v0 = xs[0], v1 = xs[1];
    bf16x8 w;
    w[0] = (bf16)v0.x; w[1] = (bf16)v0.y; w[2] = (bf16)v0.z; w[3] = (bf16)v0.w;
    w[4] = (bf16)v1.x; w[5] = (bf16)v1.y; w[6] = (bf16)v1.z; w[7] = (bf16)v1.w;
    bf16* xbf = (bf16*)((char*)attn_out + (size_t)win * 131072 + 65536);
    *(bf16x8*)&xbf[lrow * 256 + col] = w;
  }
}

// ---- K1: QKV as a real GEMM (m97 anatomy): A=x_bf16 [131072][256],
// B=qkv_wb [768][256] (row = output col), C=[131072][768].
// Grid 1024x6: bid -> mt=bid/6 (128-row tile = windows 2mt,2mt+1), nt=bid%6
// (128-col panel). 4 waves in 2x2; wave computes 64x64 via 4x4 16x16 frags.
// K-loop: 8 steps of BK=32; LDS As/Bs [128][40] bf16 (80 B stride -> 2-way
// bank aliasing only, free per m136); per wave per step: 8 ds_read_b128 +
// 16 MFMA (the measured-good ratio). Reg-staged (4x bf16x8 load + 4x
// ds_write_b128 per thread per step).
__launch_bounds__(256, 3)
__global__ void qkv_kernel(const float* __restrict__ qkv_b,
                           const bf16* __restrict__ qkv_wb,
                           float* __restrict__ out,
                           float* __restrict__ attn_out) {
  __shared__ __align__(16) bf16 As[128 * 40];
  __shared__ __align__(16) bf16 Bs[128 * 40];

  const int t = threadIdx.x;
  const int wave = t >> 6;
  const int lane = t & 63;
  const int l16 = lane & 15;
  const int quad = lane >> 4;
  const int bid = blockIdx.x;
  const int mt = bid / 6;
  const int nt = bid % 6;
  const int wr = wave >> 1;
  const int wc = wave & 1;
  const f32x4 fz = {0.f, 0.f, 0.f, 0.f};

  // staging map: thread covers (row r0, slot s0) and (row 64+r0, slot s0)
  const int r0 = t >> 2;
  const int s0 = t & 3;

  const bf16* xA0 = (const bf16*)((char*)attn_out + (size_t)(2 * mt) * 131072 + 65536);
  const bf16* xA1 = (const bf16*)((char*)attn_out + (size_t)(2 * mt + 1) * 131072 + 65536);
  const bf16* wB  = qkv_wb + (size_t)(nt * 128) * 256;

  f32x4 acc[4][4];
#pragma unroll
  for (int i = 0; i < 4; ++i)
#pragma unroll
    for (int j = 0; j < 4; ++j) acc[i][j] = fz;

#pragma unroll 1
  for (int ks = 0; ks < 8; ++ks) {
    const int kc = ks * 32 + s0 * 8;
    // global -> regs (A two halves, B two halves)
    bf16x8 a0 = *(const bf16x8*)&xA0[r0 * 256 + kc];
    bf16x8 a1 = *(const bf16x8*)&xA1[r0 * 256 + kc];
    bf16x8 b0 = *(const bf16x8*)&wB[r0 * 256 + kc];
    bf16x8 b1 = *(const bf16x8*)&wB[(64 + r0) * 256 + kc];
    __syncthreads();  // prev step's ds_reads complete before overwrite
    *(bf16x8*)&As[r0 * 40 + s0 * 8] = a0;
    *(bf16x8*)&As[(64 + r0) * 40 + s0 * 8] = a1;
    *(bf16x8*)&Bs[r0 * 40 + s0 * 8] = b0;
    *(bf16x8*)&Bs[(64 + r0) * 40 + s0 * 8] = b1;
    __syncthreads();  // staged tile visible
    bf16x8 af[4], bf_[4];
#pragma unroll
    for (int mf = 0; mf < 4; ++mf)
      af[mf] = *(const bf16x8*)&As[(wr * 64 + mf * 16 + l16) * 40 + quad * 8];
#pragma unroll
    for (int nf = 0; nf < 4; ++nf)
      bf_[nf] = *(const bf16x8*)&Bs[(wc * 64 + nf * 16 + l16) * 40 + quad * 8];
#pragma unroll
    for (int mf = 0; mf < 4; ++mf)
#pragma unroll
      for (int nf = 0; nf < 4; ++nf)
        acc[mf][nf] = MFMA16(af[mf], bf_[nf], acc[mf][nf]);
  }

  // epilogue: +bias, scale q, scatter to qk stash / v stash (bf16)
#pragma unroll
  for (int nf = 0; nf < 4; ++nf) {
    const int gcol = nt * 128 + wc * 64 + nf * 16 + l16;
    const float qb = qkv_b[gcol];
    const float sc = (gcol < 256) ? kScale : 1.0f;
#pragma unroll
    for (int mf = 0; mf < 4; ++mf)
#pragma unroll
      for (int rr = 0; rr < 4; ++rr) {
        const int grow = mt * 128 + wr * 64 + mf * 16 + quad * 4 + rr;
        const int win = grow >> 6;
        const int lrow = grow & 63;
        const float val = (acc[mf][nf][rr] + qb) * sc;
        if (gcol < 512) {
          bf16* qkst = (bf16*)((char*)attn_out + (size_t)win * 131072);
          qkst[lrow * 512 + gcol] = (bf16)val;
        } else {
          bf16* vst = (bf16*)((char*)out + (size_t)win * 65536);
          vst[lrow * 256 + (gcol - 512)] = (bf16)val;
        }
      }
  }
}

// ---- K2: attention. q-frags in regs, k in LDS (read-only all heads),
// v double-buffered+transposed per head, one barrier per head.
__launch_bounds__(256, 3)
__global__ void attn2_kernel(const float* __restrict__ biasf,
                             float* __restrict__ out,
                             float* __restrict__ attn_out) {
  __shared__ __align__(16) bf16 kl[64 * 264];   // k, all heads (cols 0..255)
  __shared__ __align__(16) bf16 vT[2][32 * 72]; // per-head v^T [d_local][token]
  __shared__ __align__(16) bf16 Pb[64 * 72];    // wave-private P

  const int t = threadIdx.x;
  const int wave = t >> 6;
  const int lane = t & 63;
  const int l16 = lane & 15;
  const int quad = lane >> 4;
  const int b = blockIdx.x;
  const int mrow = wave * 16 + l16;
  const f32x4 fz = {0.f, 0.f, 0.f, 0.f};

  const bf16* qkst = (const bf16*)(attn_out + (size_t)b * 32768);
  const bf16* vst  = (const bf16*)(out + (size_t)b * 16384);
  bf16* ost = (bf16*)(out + (size_t)b * 16384) + 16384;  // O stash [64][256]

  // q A-fragments for all 8 heads -> 32 VGPRs
  bf16x8 qf[8];
#pragma unroll
  for (int h = 0; h < 8; ++h)
    qf[h] = *(const bf16x8*)&qkst[mrow * 512 + h * 32 + quad * 8];

  // k -> LDS [64][264] (stash cols 256..511)
  {
    int row = t >> 2, part = t & 3;
#pragma unroll
    for (int j = 0; j < 8; ++j) {
      bf16x8 v = *(const bf16x8*)&qkst[row * 512 + 256 + part * 64 + j * 8];
      *(bf16x8*)&kl[row * 264 + part * 64 + j * 8] = v;
    }
  }
  // v head 0 -> vT[0]
  {
    int tok = t >> 2, dp = t & 3;
    bf16x8 v = *(const bf16x8*)&vst[tok * 256 + dp * 8];
#pragma unroll
    for (int j = 0; j < 8; ++j) vT[0][(dp * 8 + j) * 72 + tok] = v[j];
  }
  __syncthreads();  // staging visible; all qkst reads drained (attn writes
                    // below may clobber the stash region safely)

#pragma unroll
  for (int h = 0; h < 8; ++h) {
    // prefetch next head's v (global -> regs; written to LDS after PV)
    int tok = t >> 2, dp = t & 3;
    bf16x8 vnext;
    if (h < 7) vnext = *(const bf16x8*)&vst[tok * 256 + (h + 1) * 32 + dp * 8];

    f32x4 bfrag[4];
    const f32x4* bp4 = (const f32x4*)(biasf + h * 4096 + wave * 1024);
#pragma unroll
    for (int ct = 0; ct < 4; ++ct) bfrag[ct] = bp4[ct * 64 + lane];

    // S = q_h k_h^T + bias (K=32 -> 1 MFMA per 16x16 tile)
    f32x4 s[4];
#pragma unroll
    for (int ct = 0; ct < 4; ++ct) {
      bf16x8 bS = *(const bf16x8*)&kl[(ct * 16 + l16) * 264 + h * 32 + quad * 8];
      s[ct] = MFMA16(qf[h], bS, bfrag[ct]);
    }

    // softmax over j
#pragma unroll
    for (int r = 0; r < 4; ++r) {
      float m = fmaxf(fmaxf(s[0][r], s[1][r]), fmaxf(s[2][r], s[3][r]));
#pragma unroll
      for (int off = 8; off; off >>= 1) m = fmaxf(m, __shfl_xor(m, off));
      float e0 = __expf(s[0][r] - m);
      float e1 = __expf(s[1][r] - m);
      float e2 = __expf(s[2][r] - m);
      float e3 = __expf(s[3][r] - m);
      float sum = (e0 + e1) + (e2 + e3);
#pragma unroll
      for (int off = 8; off; off >>= 1) sum += __shfl_xor(sum, off);
      float is = 1.0f / sum;
      s[0][r] = e0 * is; s[1][r] = e1 * is; s[2][r] = e2 * is; s[3][r] = e3 * is;
    }

    // attn (fp32 global) + P (bf16 LDS, wave-private)
    float* ao = attn_out + ((size_t)(b * 8 + h) << 12);
#pragma unroll
    for (int ct = 0; ct < 4; ++ct)
#pragma unroll
      for (int r = 0; r < 4; ++r) {
        int i = wave * 16 + quad * 4 + r;
        int j = ct * 16 + l16;
        float pv = s[ct][r];
        ao[i * 64 + j] = pv;
        Pb[i * 72 + j] = (bf16)pv;
      }

    // O_h = P @ V
    f32x4 o[2];
    o[0] = fz; o[1] = fz;
#pragma unroll
    for (int ks = 0; ks < 2; ++ks) {
      bf16x8 aP = *(const bf16x8*)&Pb[mrow * 72 + ks * 32 + quad * 8];
#pragma unroll
      for (int nt = 0; nt < 2; ++nt) {
        bf16x8 bV = *(const bf16x8*)&vT[h & 1][(nt * 16 + l16) * 72 + ks * 32 + quad * 8];
        o[nt] = MFMA16(aP, bV, o[nt]);
      }
    }

    // O -> out-region stash
#pragma unroll
    for (int nt = 0; nt < 2; ++nt)
#pragma unroll
      for (int r = 0; r < 4; ++r)
        ost[(wave * 16 + quad * 4 + r) * 256 + h * 32 + nt * 16 + l16] =
            (bf16)o[nt][r];

    // vT[(h+1)&1]: last read at PV(h-1) (before barrier h-1); write here;
    // next read at PV(h+1) (after barrier h). Single barrier per head.
    if (h < 7) {
#pragma unroll
      for (int j = 0; j < 8; ++j)
        vT[(h + 1) & 1][(dp * 8 + j) * 72 + tok] = vnext[j];
    }
    __syncthreads();
  }
}

// ---- K3: proj GEMM. 1 window/block; barrier between stash reads and the
// out stores that overwrite the stash (cross-wave clobber).
__launch_bounds__(256, 3)
__global__ void proj_kernel(const float* __restrict__ proj_b,
                            const bf16* __restrict__ proj_wb,
                            float* __restrict__ out) {
  const int t = threadIdx.x;
  const int wave = t >> 6;
  const int lane = t & 63;
  const int l16 = lane & 15;
  const int quad = lane >> 4;
  const int b = blockIdx.x;
  const int mrow = wave * 16 + l16;
  const f32x4 fz = {0.f, 0.f, 0.f, 0.f};

  const bf16* ost = (const bf16*)(out + (size_t)b * 16384) + 16384;
  bf16x8 oafr[8];
#pragma unroll
  for (int kt = 0; kt < 8; ++kt)
    oafr[kt] = *(const bf16x8*)&ost[mrow * 256 + kt * 32 + quad * 8];

  f32x4 acc[16];
#pragma unroll
  for (int i = 0; i < 16; ++i) acc[i] = fz;
#pragma unroll
  for (int nt = 0; nt < 16; ++nt) {
    const bf16* wp = proj_wb + (nt * 16 + l16) * 256 + quad * 8;
    bf16x8 bfr[8];
#pragma unroll
    for (int kt = 0; kt < 8; ++kt) bfr[kt] = *(const bf16x8*)&wp[kt * 32];
#pragma unroll
    for (int kt = 0; kt < 8; ++kt) acc[nt] = MFMA16(oafr[kt], bfr[kt], acc[nt]);
  }
  __syncthreads();  // all waves' stash reads complete before stores clobber

  float* op = out + (size_t)b * 16384;
#pragma unroll
  for (int nt = 0; nt < 16; ++nt) {
    float pb = proj_b[nt * 16 + l16];
#pragma unroll
    for (int r = 0; r < 4; ++r)
      op[(wave * 16 + quad * 4 + r) * 256 + nt * 16 + l16] = acc[nt][r] + pb;
  }
}

extern "C" void kernel_launch(void* const* d_in, const int* in_sizes, int n_in,
                              void* d_out, int out_size, void* d_ws, size_t ws_size,
                              hipStream_t stream) {
  const float* x          = (const float*)d_in[0];
  const float* qkv_w      = (const float*)d_in[1];
  const float* qkv_b      = (const float*)d_in[2];
  const float* proj_w     = (const float*)d_in[3];
  const float* proj_b     = (const float*)d_in[4];
  const float* bias_table = (const float*)d_in[5];
  const int*   rel_idx    = (const int*)d_in[6];

  bf16*  qkv_wb = (bf16*)((char*)d_ws + kWqkvOff);
  bf16*  proj_wb = (bf16*)((char*)d_ws + kWprojOff);
  float* biasf  = (float*)((char*)d_ws + kBiasOff);

  float* out      = (float*)d_out;
  float* attn_out = out + kOut0;

  prep_kernel<<<17536, 256, 0, stream>>>(x, qkv_w, proj_w, bias_table, rel_idx,
                                         qkv_wb, proj_wb, biasf, attn_out);
  qkv_kernel<<<6144, 256, 0, stream>>>(qkv_b, qkv_wb, out, attn_out);
  attn2_kernel<<<kB, 256, 0, stream>>>(biasf, out, attn_out);
  proj_kernel<<<kB, 256, 0, stream>>>(proj_b, proj_wb, out);
}